// Round 12
// baseline (81.060 us; speedup 1.0000x reference)
//
#include <hip/hip_runtime.h>
#include <hip/hip_bf16.h>
#include <stdint.h>

typedef unsigned short u16;
typedef unsigned int   u32;
typedef unsigned long long u64;

#define N_ROWS 4096
#define DIM    512
#define NT32   128         // N_ROWS / 32 tiles per side
#define NPAIR32 8256       // NT32*(NT32+1)/2 (= 8 * 1032)
#define MOD3   729         // 3^6
#define NKP    8           // k-pairs; each covers 64 k (two 16x16x32 steps)
#define NSLOT  64

typedef __attribute__((ext_vector_type(2))) long  long2v;
typedef __attribute__((ext_vector_type(2))) float f32x2;
typedef __attribute__((ext_vector_type(4))) float f32x4;

// ---- workspace layout (byte offsets) ----
// zpack: fp8 e4m3 superblocks (layout PROVEN R10/R11, absmax 0): superblock
// (R, s2) = 1 KB at ((R*8)+s2)*1024; u64 slot L*2+h; covers 16-row group R,
// k-steps 2*s2, 2*s2+1.
#define WS_ZPK  0
#define WS_SQ   (N_ROWS * DIM)              // zpack = N*D bytes
#define WS_R    (WS_SQ + N_ROWS * 4)
#define WS_GS   (WS_R + N_ROWS * 4)         // 64 f32 (zeroed by count_kernel)
#define WS_META (WS_GS + 64 * 4)            // 4 f32: lc
#define WS_LUTG (WS_META + 16)              // 1536 f32: (coef, tv) pairs

// ---------------------------------------------------------------------------
// Prep: f32 -> fp8 pack into superblock zpack (proven), row sum-of-squares,
// residues mod 729. (Histogram moved into count_kernel -- no global memset.)
// ---------------------------------------------------------------------------
__global__ __launch_bounds__(256)
void prep_kernel(const float* __restrict__ z, const int* __restrict__ idx,
                 u64* __restrict__ zpack, float* __restrict__ sq,
                 int* __restrict__ rres)
{
    const int lane = threadIdx.x & 63;
    const int row  = blockIdx.x * 4 + (threadIdx.x >> 6);
    const float4* zr = reinterpret_cast<const float4*>(z + (size_t)row * DIM) + lane * 2;
    float4 v0 = zr[0], v1 = zr[1];
    float f[8] = {v0.x, v0.y, v0.z, v0.w, v1.x, v1.y, v1.z, v1.w};
    float ss = 0.f;
#pragma unroll
    for (int k = 0; k < 8; ++k) ss += f[k] * f[k];
    int lo = __builtin_amdgcn_cvt_pk_fp8_f32(f[0], f[1], 0, false);
    lo     = __builtin_amdgcn_cvt_pk_fp8_f32(f[2], f[3], lo, true);
    int hi = __builtin_amdgcn_cvt_pk_fp8_f32(f[4], f[5], 0, false);
    hi     = __builtin_amdgcn_cvt_pk_fp8_f32(f[6], f[7], hi, true);
    const u64 pk = (u64)(u32)lo | ((u64)(u32)hi << 32);
    zpack[((size_t)((row >> 4) * 8 + (lane >> 3)) << 7)
          + ((lane & 3) * 16 + (row & 15)) * 2 + ((lane >> 2) & 1)] = pk;
#pragma unroll
    for (int off = 32; off > 0; off >>= 1) ss += __shfl_down(ss, off, 64);
    if (lane == 0) {
        sq[row] = ss;
        rres[row] = idx[row] % MOD3;   // idx >= 0
    }
}

// ---------------------------------------------------------------------------
// Count: builds the residue histogram IN LDS from rres (no global hist, no
// memset node), derives exact per-level pair counts, writes the 729-entry
// (coef, tv) LUT + lc, and zeroes gS for pair_kernel's atomics.
// cnt(val>=t) = sum_c C(h_t[c],2) - E ; E cancels in cnt_v differences.
// ---------------------------------------------------------------------------
__global__ __launch_bounds__(768)
void count_kernel(const int* __restrict__ rres, float* __restrict__ lutg,
                  float* __restrict__ meta, float* __restrict__ gS)
{
    __shared__ u32 h[736];
    __shared__ u32 T[8];
    __shared__ float cf[8];
    const int tid = threadIdx.x;
    if (tid < 736) h[tid] = 0u;
    if (tid < 8)   T[tid] = 0u;
    if (tid < NSLOT) gS[tid] = 0.f;      // zero accumulators for pair_kernel
    __syncthreads();
    for (int i = tid; i < N_ROWS; i += 768) atomicAdd(&h[rres[i]], 1u);
    __syncthreads();
    if (tid < 729) { u32 x = h[tid]; if (x > 1) atomicAdd(&T[6], x * (x - 1) / 2u); }
    __syncthreads();
    if (tid < 243) h[tid] = h[tid] + h[tid + 243] + h[tid + 486];
    __syncthreads();
    if (tid < 243) { u32 x = h[tid]; if (x > 1) atomicAdd(&T[5], x * (x - 1) / 2u); }
    __syncthreads();
    if (tid < 81) h[tid] = h[tid] + h[tid + 81] + h[tid + 162];
    __syncthreads();
    if (tid < 81) { u32 x = h[tid]; if (x > 1) atomicAdd(&T[4], x * (x - 1) / 2u); }
    __syncthreads();
    if (tid < 27) h[tid] = h[tid] + h[tid + 27] + h[tid + 54];
    __syncthreads();
    if (tid < 27) { u32 x = h[tid]; if (x > 1) atomicAdd(&T[3], x * (x - 1) / 2u); }
    __syncthreads();
    if (tid < 9) h[tid] = h[tid] + h[tid + 9] + h[tid + 18];
    __syncthreads();
    if (tid < 9) { u32 x = h[tid]; if (x > 1) atomicAdd(&T[2], x * (x - 1) / 2u); }
    __syncthreads();
    if (tid < 3) h[tid] = h[tid] + h[tid + 3] + h[tid + 6];
    __syncthreads();
    if (tid < 3) { u32 x = h[tid]; if (x > 1) atomicAdd(&T[1], x * (x - 1) / 2u); }
    __syncthreads();
    if (tid == 0) {
        u32 cnt[6];
        cnt[0] = (u32)((u64)N_ROWS * (N_ROWS - 1) / 2) - T[1];
        cnt[1] = T[1] - T[2]; cnt[2] = T[2] - T[3]; cnt[3] = T[3] - T[4];
        cnt[4] = T[4] - T[5]; cnt[5] = T[5] - T[6];
        const float w[6] = {1.f, 0.5f, 1.f / 3.f, 0.25f, 0.2f, 1.f / 6.f};
        float lc = 0.f;
#pragma unroll
        for (int v = 0; v < 6; ++v) {
            const bool use = cnt[v] >= 2u;
            cf[v] = use ? w[v] / (float)cnt[v] : 0.f;
            lc += use ? 1.f : 0.f;
        }
        cf[6] = 0.f; cf[7] = 0.f;
        meta[0] = (lc > 0.f) ? lc : 1.f;
    }
    __syncthreads();
    // LUT: 768 entries (729 real + zero pad to 1536 floats for width-16 glds)
    {
        const int e = tid;
        float coef = 0.f, tv = 0.f;
        if (e < 729) {
            int v = 6;
            if (e != 0) { v = 0; int y = e; while (v < 6 && y % 3 == 0) { y /= 3; ++v; } }
            const float tvs[7] = {1.f, 1.f / 3.f, 1.f / 9.f, 1.f / 27.f,
                                  1.f / 81.f, 1.f / 243.f, 0.f};
            coef = cf[v];
            tv   = tvs[v];
        }
        lutg[2 * e]     = coef;
        lutg[2 * e + 1] = tv;
    }
}

// ---------------------------------------------------------------------------
// Main (byte-identical to R11's pair_kernel, proven absmax 0): ONE WAVE per
// block, one 32x32 tile pair, fp8 operands, glds + counted-vmcnt pipeline,
// LUT epilogue (single scalar accumulator).
// ---------------------------------------------------------------------------
template<bool DIAG>
__device__ __forceinline__ void epilogue_acc(
    const f32x4 (&acc)[2][2], const float* sqIJ, const int* rIJ,
    const float* lut, int lane, float& S)
{
    const int rbase = (lane >> 4) * 4;   // C/D: row = (lane>>4)*4+q, col = lane&15
    const int cbase = lane & 15;
#pragma unroll
    for (int m = 0; m < 2; ++m)
#pragma unroll
        for (int n = 0; n < 2; ++n)
#pragma unroll
            for (int q = 0; q < 4; ++q) {
                const int il = m * 16 + rbase + q;
                const int jl = n * 16 + cbase;
                float d2 = fmaxf(sqIJ[il] + sqIJ[32 + jl] - 2.0f * acc[m][n][q], 0.f);
                const float dist = __builtin_amdgcn_sqrtf(d2);
                int dm = rIJ[il] - rIJ[32 + jl];
                dm += (dm >> 31) & MOD3;               // [0, 729)
                const f32x2 ct = *reinterpret_cast<const f32x2*>(&lut[dm * 2]);
                float coef = ct[0];
                if (DIAG) coef = (jl > il) ? coef : 0.f;
                const float dd = dist - ct[1];
                S += coef * dd * dd;
            }
}

__global__ __launch_bounds__(64, 4)
void pair_kernel(const u64* __restrict__ zpack, const float* __restrict__ sq,
                 const int* __restrict__ rres, const float* __restrict__ lutg,
                 float* __restrict__ gS)
{
    __shared__ __align__(16) u64   sb[2][4][128];   // 8 KB staging (2 A + 2 B)
    __shared__ __align__(16) float lut[1536];       // 6 KB LUT
    __shared__ __align__(16) float sqIJ[64];        // [0..31]=I, [32..63]=J
    __shared__ __align__(16) int   rIJ[64];

    const int lane = threadIdx.x;

    // bijective XCD swizzle (8256 = 8 * 1032)
    const int wg = (blockIdx.x & 7) * (NPAIR32 / 8) + (blockIdx.x >> 3);
    int t = wg, ti = 0, rem = NT32;
    while (t >= rem) { t -= rem; ++ti; --rem; }
    const int tj = ti + t;
    const int I0 = ti * 32, J0 = tj * 32;

    // aux staging (8 glds): sqIJ, rIJ (per-lane conditional src), LUT (6x1KB)
    const int gsrc = (lane < 32) ? (I0 + lane) : (J0 + lane - 32);
    __builtin_amdgcn_global_load_lds(
        (const __attribute__((address_space(1))) u32*)(sq + gsrc),
        (__attribute__((address_space(3))) u32*)sqIJ, 4, 0, 0);
    __builtin_amdgcn_global_load_lds(
        (const __attribute__((address_space(1))) u32*)(rres + gsrc),
        (__attribute__((address_space(3))) u32*)rIJ, 4, 0, 0);
#pragma unroll
    for (int i = 0; i < 6; ++i)
        __builtin_amdgcn_global_load_lds(
            (const __attribute__((address_space(1))) u32*)(lutg + i * 256 + lane * 4),
            (__attribute__((address_space(3))) u32*)&lut[i * 256], 16, 0, 0);

    const int RA = 2 * ti, RB = 2 * tj;   // 16-row group bases

#define STAGE(buf, kp)                                                         \
    {                                                                          \
        _Pragma("unroll")                                                      \
        for (int g = 0; g < 2; ++g) {                                          \
            __builtin_amdgcn_global_load_lds(                                  \
                (const __attribute__((address_space(1))) u32*)                 \
                    (zpack + (((size_t)(RA + g) * 8 + (kp)) << 7) + lane * 2), \
                (__attribute__((address_space(3))) u32*)&sb[buf][g][0],        \
                16, 0, 0);                                                     \
            __builtin_amdgcn_global_load_lds(                                  \
                (const __attribute__((address_space(1))) u32*)                 \
                    (zpack + (((size_t)(RB + g) * 8 + (kp)) << 7) + lane * 2), \
                (__attribute__((address_space(3))) u32*)&sb[buf][2 + g][0],    \
                16, 0, 0);                                                     \
        }                                                                      \
    }

    f32x4 acc[2][2];
#pragma unroll
    for (int m = 0; m < 2; ++m)
#pragma unroll
        for (int n = 0; n < 2; ++n) acc[m][n] = (f32x4){0.f, 0.f, 0.f, 0.f};

    STAGE(0, 0);
#pragma unroll
    for (int kp = 0; kp < NKP; ++kp) {
        const int buf = kp & 1;
        if (kp + 1 < NKP) {
            STAGE(buf ^ 1, kp + 1);
            // kp=0: 8 aux + 4 (kp0) + 4 (kp1) in flight -> vmcnt(4) retires
            // aux+kp0, leaves kp1. kp>=1: retires kp's 4, leaves kp+1's 4.
            asm volatile("s_waitcnt vmcnt(4)" ::: "memory");
        } else {
            asm volatile("s_waitcnt vmcnt(0)" ::: "memory");
        }
        __builtin_amdgcn_sched_barrier(0);
        long2v A[2], B[2];
#pragma unroll
        for (int g = 0; g < 2; ++g) {
            A[g] = reinterpret_cast<const long2v*>(&sb[buf][g][0])[lane];
            B[g] = reinterpret_cast<const long2v*>(&sb[buf][2 + g][0])[lane];
        }
#pragma unroll
        for (int h = 0; h < 2; ++h)
#pragma unroll
            for (int m = 0; m < 2; ++m)
#pragma unroll
                for (int n = 0; n < 2; ++n)
                    acc[m][n] = __builtin_amdgcn_mfma_f32_16x16x32_fp8_fp8(
                        A[m][h], B[n][h], acc[m][n], 0, 0, 0);
    }
#undef STAGE

    // ---- fused epilogue (1 wave, no barriers; LDS landed via vmcnt above) --
    float S = 0.f;
    if (ti == tj) epilogue_acc<true >(acc, sqIJ, rIJ, lut, lane, S);
    else          epilogue_acc<false>(acc, sqIJ, rIJ, lut, lane, S);

#pragma unroll
    for (int off = 32; off > 0; off >>= 1) S += __shfl_xor(S, off, 64);
    if (lane == 0) atomicAdd(&gS[blockIdx.x & (NSLOT - 1)], S);
}

// ---------------------------------------------------------------------------
__global__ __launch_bounds__(64)
void finalize_kernel(const float* __restrict__ gS,
                     const float* __restrict__ meta, float* __restrict__ out)
{
    const int lane = threadIdx.x;
    float s = gS[lane];
#pragma unroll
    for (int off = 32; off > 0; off >>= 1) s += __shfl_xor(s, off, 64);
    if (lane == 0) out[0] = s / meta[0];
}

// ---------------------------------------------------------------------------
extern "C" void kernel_launch(void* const* d_in, const int* in_sizes, int n_in,
                              void* d_out, int out_size, void* d_ws, size_t ws_size,
                              hipStream_t stream)
{
    const float* z   = (const float*)d_in[0];
    const int*   idx = (const int*)d_in[1];
    char* ws = (char*)d_ws;
    u64*   zpk  = (u64*)(ws + WS_ZPK);
    float* sq   = (float*)(ws + WS_SQ);
    int*   rres = (int*)(ws + WS_R);
    float* gS   = (float*)(ws + WS_GS);
    float* meta = (float*)(ws + WS_META);
    float* lutg = (float*)(ws + WS_LUTG);
    float* out  = (float*)d_out;

    prep_kernel<<<N_ROWS / 4, 256, 0, stream>>>(z, idx, zpk, sq, rres);
    count_kernel<<<1, 768, 0, stream>>>(rres, lutg, meta, gS);
    pair_kernel<<<NPAIR32, 64, 0, stream>>>(zpk, sq, rres, lutg, gS);
    finalize_kernel<<<1, 64, 0, stream>>>(gS, meta, out);
}

// Round 13
// 47.388 us; speedup vs baseline: 1.7106x; 1.7106x over previous
//
#include <hip/hip_runtime.h>
#include <hip/hip_bf16.h>
#include <stdint.h>

typedef unsigned short u16;
typedef unsigned int   u32;
typedef unsigned long long u64;

#define N_ROWS 4096
#define DIM    512
#define NT64   64          // N_ROWS / 64 tiles per side
#define NPAIR64 2080       // NT64*(NT64+1)/2 (= 8 * 260)
#define MOD3   729         // 3^6
#define NKP    8           // k-pairs; each covers 64 k (two 16x16x32 steps)
#define NSLOT  64

typedef __attribute__((ext_vector_type(2))) long  long2v;
typedef __attribute__((ext_vector_type(2))) float f32x2;
typedef __attribute__((ext_vector_type(4))) float f32x4;

// ---- workspace layout (byte offsets) ----
// zpack: fp8 e4m3 superblocks (PROVEN R10-R12): superblock (R, s2) = 1 KB at
// ((R*8)+s2)*1024; u64 slot L*2+h; covers 16-row group R, k-steps 2s2, 2s2+1.
#define WS_ZPK  0
#define WS_SQ   (N_ROWS * DIM)
#define WS_R    (WS_SQ + N_ROWS * 4)
#define WS_GS   (WS_R + N_ROWS * 4)         // 64 f32 (zeroed by count_kernel)
#define WS_META (WS_GS + 64 * 4)            // 4 f32: lc
#define WS_LUTG (WS_META + 16)              // 1536 f32: (coef, tv) pairs

// ---------------------------------------------------------------------------
// Prep (PROVEN): f32 -> fp8 pack into superblock zpack, row sum-of-squares,
// residues mod 729.
// ---------------------------------------------------------------------------
__global__ __launch_bounds__(256)
void prep_kernel(const float* __restrict__ z, const int* __restrict__ idx,
                 u64* __restrict__ zpack, float* __restrict__ sq,
                 int* __restrict__ rres)
{
    const int lane = threadIdx.x & 63;
    const int row  = blockIdx.x * 4 + (threadIdx.x >> 6);
    const float4* zr = reinterpret_cast<const float4*>(z + (size_t)row * DIM) + lane * 2;
    float4 v0 = zr[0], v1 = zr[1];
    float f[8] = {v0.x, v0.y, v0.z, v0.w, v1.x, v1.y, v1.z, v1.w};
    float ss = 0.f;
#pragma unroll
    for (int k = 0; k < 8; ++k) ss += f[k] * f[k];
    int lo = __builtin_amdgcn_cvt_pk_fp8_f32(f[0], f[1], 0, false);
    lo     = __builtin_amdgcn_cvt_pk_fp8_f32(f[2], f[3], lo, true);
    int hi = __builtin_amdgcn_cvt_pk_fp8_f32(f[4], f[5], 0, false);
    hi     = __builtin_amdgcn_cvt_pk_fp8_f32(f[6], f[7], hi, true);
    const u64 pk = (u64)(u32)lo | ((u64)(u32)hi << 32);
    zpack[((size_t)((row >> 4) * 8 + (lane >> 3)) << 7)
          + ((lane & 3) * 16 + (row & 15)) * 2 + ((lane >> 2) & 1)] = pk;
#pragma unroll
    for (int off = 32; off > 0; off >>= 1) ss += __shfl_down(ss, off, 64);
    if (lane == 0) {
        sq[row] = ss;
        rres[row] = idx[row] % MOD3;   // idx >= 0
    }
}

// ---------------------------------------------------------------------------
// Count (PROVEN R12): LDS histogram from rres, exact per-level counts, the
// 729-entry (coef, tv) LUT, lc, and zeroes gS.
// ---------------------------------------------------------------------------
__global__ __launch_bounds__(768)
void count_kernel(const int* __restrict__ rres, float* __restrict__ lutg,
                  float* __restrict__ meta, float* __restrict__ gS)
{
    __shared__ u32 h[736];
    __shared__ u32 T[8];
    __shared__ float cf[8];
    const int tid = threadIdx.x;
    if (tid < 736) h[tid] = 0u;
    if (tid < 8)   T[tid] = 0u;
    if (tid < NSLOT) gS[tid] = 0.f;
    __syncthreads();
    for (int i = tid; i < N_ROWS; i += 768) atomicAdd(&h[rres[i]], 1u);
    __syncthreads();
    if (tid < 729) { u32 x = h[tid]; if (x > 1) atomicAdd(&T[6], x * (x - 1) / 2u); }
    __syncthreads();
    if (tid < 243) h[tid] = h[tid] + h[tid + 243] + h[tid + 486];
    __syncthreads();
    if (tid < 243) { u32 x = h[tid]; if (x > 1) atomicAdd(&T[5], x * (x - 1) / 2u); }
    __syncthreads();
    if (tid < 81) h[tid] = h[tid] + h[tid + 81] + h[tid + 162];
    __syncthreads();
    if (tid < 81) { u32 x = h[tid]; if (x > 1) atomicAdd(&T[4], x * (x - 1) / 2u); }
    __syncthreads();
    if (tid < 27) h[tid] = h[tid] + h[tid + 27] + h[tid + 54];
    __syncthreads();
    if (tid < 27) { u32 x = h[tid]; if (x > 1) atomicAdd(&T[3], x * (x - 1) / 2u); }
    __syncthreads();
    if (tid < 9) h[tid] = h[tid] + h[tid + 9] + h[tid + 18];
    __syncthreads();
    if (tid < 9) { u32 x = h[tid]; if (x > 1) atomicAdd(&T[2], x * (x - 1) / 2u); }
    __syncthreads();
    if (tid < 3) h[tid] = h[tid] + h[tid + 3] + h[tid + 6];
    __syncthreads();
    if (tid < 3) { u32 x = h[tid]; if (x > 1) atomicAdd(&T[1], x * (x - 1) / 2u); }
    __syncthreads();
    if (tid == 0) {
        u32 cnt[6];
        cnt[0] = (u32)((u64)N_ROWS * (N_ROWS - 1) / 2) - T[1];
        cnt[1] = T[1] - T[2]; cnt[2] = T[2] - T[3]; cnt[3] = T[3] - T[4];
        cnt[4] = T[4] - T[5]; cnt[5] = T[5] - T[6];
        const float w[6] = {1.f, 0.5f, 1.f / 3.f, 0.25f, 0.2f, 1.f / 6.f};
        float lc = 0.f;
#pragma unroll
        for (int v = 0; v < 6; ++v) {
            const bool use = cnt[v] >= 2u;
            cf[v] = use ? w[v] / (float)cnt[v] : 0.f;
            lc += use ? 1.f : 0.f;
        }
        cf[6] = 0.f; cf[7] = 0.f;
        meta[0] = (lc > 0.f) ? lc : 1.f;
    }
    __syncthreads();
    {
        const int e = tid;
        float coef = 0.f, tv = 0.f;
        if (e < 729) {
            int v = 6;
            if (e != 0) { v = 0; int y = e; while (v < 6 && y % 3 == 0) { y /= 3; ++v; } }
            const float tvs[7] = {1.f, 1.f / 3.f, 1.f / 9.f, 1.f / 27.f,
                                  1.f / 81.f, 1.f / 243.f, 0.f};
            coef = cf[v];
            tv   = tvs[v];
        }
        lutg[2 * e]     = coef;
        lutg[2 * e + 1] = tv;
    }
}

// ---------------------------------------------------------------------------
// Main: R10's PROVEN 64x64 one-wave k-loop (glds superblocks + counted
// vmcnt(8), zero barriers) + LUT epilogue reading GLOBAL lutg (L2-resident
// 6 KB; 64 independent gathers/thread -> ILP hides latency; no LDS staging).
// ---------------------------------------------------------------------------
template<bool DIAG>
__device__ __forceinline__ void epilogue_acc(
    const f32x4 (&acc)[4][4], const float* sqI, const float* sqJ,
    const int* rI, const int* rJ, const float* __restrict__ lutg,
    int lane, float& S)
{
    const int rbase = (lane >> 4) * 4;   // C/D: row=(lane>>4)*4+q, col=lane&15
    const int cbase = lane & 15;
#pragma unroll
    for (int m = 0; m < 4; ++m) {
        const int il0 = m * 16 + rbase;
#pragma unroll
        for (int n = 0; n < 4; ++n) {
            const int jl  = n * 16 + cbase;
            const float sqj = sqJ[jl];
            const int   rj  = rJ[jl];
#pragma unroll
            for (int q = 0; q < 4; ++q) {
                const int il = il0 + q;
                float d2 = fmaxf(sqI[il] + sqj - 2.0f * acc[m][n][q], 0.f);
                const float dist = __builtin_amdgcn_sqrtf(d2);
                int dm = rI[il] - rj;
                dm += (dm >> 31) & MOD3;               // [0, 729)
                const f32x2 ct = *reinterpret_cast<const f32x2*>(&lutg[dm * 2]);
                float coef = ct[0];                    // 0 for v=6 / dm=0
                if (DIAG) coef = (jl > il) ? coef : 0.f;
                const float dd = dist - ct[1];
                S += coef * dd * dd;
            }
        }
    }
}

__global__ __launch_bounds__(64, 2)
void pair_kernel(const u64* __restrict__ zpack, const float* __restrict__ sq,
                 const int* __restrict__ rres, const float* __restrict__ lutg,
                 float* __restrict__ gS)
{
    __shared__ __align__(16) u64 sb[2][8][128];   // 16 KB: 4 A + 4 B superblocks
    __shared__ float sqI[64], sqJ[64];
    __shared__ int   rI[64], rJ[64];

    const int lane = threadIdx.x;

    // bijective XCD swizzle (2080 = 8 * 260)
    const int wg = (blockIdx.x & 7) * (NPAIR64 / 8) + (blockIdx.x >> 3);
    int t = wg, ti = 0, rem = NT64;
    while (t >= rem) { t -= rem; ++ti; --rem; }
    const int tj = ti + t;
    const int I0 = ti * 64, J0 = tj * 64;

    // aux staging (4 glds; retired by the first vmcnt(8))
    __builtin_amdgcn_global_load_lds(
        (const __attribute__((address_space(1))) u32*)(sq + I0 + lane),
        (__attribute__((address_space(3))) u32*)sqI, 4, 0, 0);
    __builtin_amdgcn_global_load_lds(
        (const __attribute__((address_space(1))) u32*)(sq + J0 + lane),
        (__attribute__((address_space(3))) u32*)sqJ, 4, 0, 0);
    __builtin_amdgcn_global_load_lds(
        (const __attribute__((address_space(1))) u32*)(rres + I0 + lane),
        (__attribute__((address_space(3))) u32*)rI, 4, 0, 0);
    __builtin_amdgcn_global_load_lds(
        (const __attribute__((address_space(1))) u32*)(rres + J0 + lane),
        (__attribute__((address_space(3))) u32*)rJ, 4, 0, 0);

    const int RA = ti * 4, RB = tj * 4;   // 16-row group bases

#define STAGE(buf, kp)                                                         \
    {                                                                          \
        _Pragma("unroll")                                                      \
        for (int g = 0; g < 4; ++g) {                                          \
            __builtin_amdgcn_global_load_lds(                                  \
                (const __attribute__((address_space(1))) u32*)                 \
                    (zpack + (((size_t)(RA + g) * 8 + (kp)) << 7) + lane * 2), \
                (__attribute__((address_space(3))) u32*)&sb[buf][g][0],        \
                16, 0, 0);                                                     \
            __builtin_amdgcn_global_load_lds(                                  \
                (const __attribute__((address_space(1))) u32*)                 \
                    (zpack + (((size_t)(RB + g) * 8 + (kp)) << 7) + lane * 2), \
                (__attribute__((address_space(3))) u32*)&sb[buf][4 + g][0],    \
                16, 0, 0);                                                     \
        }                                                                      \
    }

    f32x4 acc[4][4];
#pragma unroll
    for (int m = 0; m < 4; ++m)
#pragma unroll
        for (int n = 0; n < 4; ++n) acc[m][n] = (f32x4){0.f, 0.f, 0.f, 0.f};

    STAGE(0, 0);
#pragma unroll
    for (int kp = 0; kp < NKP; ++kp) {
        const int buf = kp & 1;
        if (kp + 1 < NKP) {
            STAGE(buf ^ 1, kp + 1);
            asm volatile("s_waitcnt vmcnt(8)" ::: "memory");
        } else {
            asm volatile("s_waitcnt vmcnt(0)" ::: "memory");
        }
        __builtin_amdgcn_sched_barrier(0);
        long2v A[4], B[4];
#pragma unroll
        for (int g = 0; g < 4; ++g) {
            A[g] = reinterpret_cast<const long2v*>(&sb[buf][g][0])[lane];
            B[g] = reinterpret_cast<const long2v*>(&sb[buf][4 + g][0])[lane];
        }
#pragma unroll
        for (int h = 0; h < 2; ++h)
#pragma unroll
            for (int m = 0; m < 4; ++m)
#pragma unroll
                for (int n = 0; n < 4; ++n)
                    acc[m][n] = __builtin_amdgcn_mfma_f32_16x16x32_fp8_fp8(
                        A[m][h], B[n][h], acc[m][n], 0, 0, 0);
    }
#undef STAGE

    // ---- fused LUT epilogue (1 wave, no barriers) ----
    float S = 0.f;
    if (ti == tj) epilogue_acc<true >(acc, sqI, sqJ, rI, rJ, lutg, lane, S);
    else          epilogue_acc<false>(acc, sqI, sqJ, rI, rJ, lutg, lane, S);

#pragma unroll
    for (int off = 32; off > 0; off >>= 1) S += __shfl_xor(S, off, 64);
    if (lane == 0) atomicAdd(&gS[blockIdx.x & (NSLOT - 1)], S);
}

// ---------------------------------------------------------------------------
__global__ __launch_bounds__(64)
void finalize_kernel(const float* __restrict__ gS,
                     const float* __restrict__ meta, float* __restrict__ out)
{
    const int lane = threadIdx.x;
    float s = gS[lane];
#pragma unroll
    for (int off = 32; off > 0; off >>= 1) s += __shfl_xor(s, off, 64);
    if (lane == 0) out[0] = s / meta[0];
}

// ---------------------------------------------------------------------------
extern "C" void kernel_launch(void* const* d_in, const int* in_sizes, int n_in,
                              void* d_out, int out_size, void* d_ws, size_t ws_size,
                              hipStream_t stream)
{
    const float* z   = (const float*)d_in[0];
    const int*   idx = (const int*)d_in[1];
    char* ws = (char*)d_ws;
    u64*   zpk  = (u64*)(ws + WS_ZPK);
    float* sq   = (float*)(ws + WS_SQ);
    int*   rres = (int*)(ws + WS_R);
    float* gS   = (float*)(ws + WS_GS);
    float* meta = (float*)(ws + WS_META);
    float* lutg = (float*)(ws + WS_LUTG);
    float* out  = (float*)d_out;

    prep_kernel<<<N_ROWS / 4, 256, 0, stream>>>(z, idx, zpk, sq, rres);
    count_kernel<<<1, 768, 0, stream>>>(rres, lutg, meta, gS);
    pair_kernel<<<NPAIR64, 64, 0, stream>>>(zpk, sq, rres, lutg, gS);
    finalize_kernel<<<1, 64, 0, stream>>>(gS, meta, out);
}

// Round 14
// 46.174 us; speedup vs baseline: 1.7555x; 1.0263x over previous
//
#include <hip/hip_runtime.h>
#include <hip/hip_bf16.h>
#include <stdint.h>

typedef unsigned short u16;
typedef unsigned int   u32;
typedef unsigned long long u64;

#define N_ROWS 4096
#define DIM    512
#define NT64   64          // N_ROWS / 64 tiles per side
#define NPAIR64 2080       // NT64*(NT64+1)/2 (= 8 * 260)
#define MOD3   729         // 3^6
#define NKP    8           // k-pairs; each covers 64 k (two 16x16x32 steps)
#define NSLOT  64

typedef __attribute__((ext_vector_type(2))) long  long2v;
typedef __attribute__((ext_vector_type(2))) float f32x2;
typedef __attribute__((ext_vector_type(4))) float f32x4;

// ---- workspace layout (byte offsets) ----
// zpack: fp8 e4m3 superblocks (PROVEN R10-R13): superblock (R, s2) = 1 KB at
// ((R*8)+s2)*1024; u64 slot L*2+h; covers 16-row group R, k-steps 2s2, 2s2+1.
#define WS_ZPK  0
#define WS_SQ   (N_ROWS * DIM)
#define WS_R    (WS_SQ + N_ROWS * 4)
#define WS_GS   (WS_R + N_ROWS * 4)         // 64 f32 (zeroed by count_kernel)
#define WS_META (WS_GS + 64 * 4)            // 4 f32: lc
#define WS_CF8  (WS_META + 16)              // 8 x f32x2: (coef_v, tv_v)

// ---------------------------------------------------------------------------
// Prep (PROVEN): f32 -> fp8 pack into superblock zpack, row sum-of-squares,
// residues mod 729.
// ---------------------------------------------------------------------------
__global__ __launch_bounds__(256)
void prep_kernel(const float* __restrict__ z, const int* __restrict__ idx,
                 u64* __restrict__ zpack, float* __restrict__ sq,
                 int* __restrict__ rres)
{
    const int lane = threadIdx.x & 63;
    const int row  = blockIdx.x * 4 + (threadIdx.x >> 6);
    const float4* zr = reinterpret_cast<const float4*>(z + (size_t)row * DIM) + lane * 2;
    float4 v0 = zr[0], v1 = zr[1];
    float f[8] = {v0.x, v0.y, v0.z, v0.w, v1.x, v1.y, v1.z, v1.w};
    float ss = 0.f;
#pragma unroll
    for (int k = 0; k < 8; ++k) ss += f[k] * f[k];
    int lo = __builtin_amdgcn_cvt_pk_fp8_f32(f[0], f[1], 0, false);
    lo     = __builtin_amdgcn_cvt_pk_fp8_f32(f[2], f[3], lo, true);
    int hi = __builtin_amdgcn_cvt_pk_fp8_f32(f[4], f[5], 0, false);
    hi     = __builtin_amdgcn_cvt_pk_fp8_f32(f[6], f[7], hi, true);
    const u64 pk = (u64)(u32)lo | ((u64)(u32)hi << 32);
    zpack[((size_t)((row >> 4) * 8 + (lane >> 3)) << 7)
          + ((lane & 3) * 16 + (row & 15)) * 2 + ((lane >> 2) & 1)] = pk;
#pragma unroll
    for (int off = 32; off > 0; off >>= 1) ss += __shfl_down(ss, off, 64);
    if (lane == 0) {
        sq[row] = ss;
        rres[row] = idx[row] % MOD3;   // idx >= 0
    }
}

// ---------------------------------------------------------------------------
// Count (math PROVEN R11-R13): LDS histogram from rres, exact per-level pair
// counts, 8-entry (coef_v, tv_v) table, lc; zeroes gS.
// ---------------------------------------------------------------------------
__global__ __launch_bounds__(768)
void count_kernel(const int* __restrict__ rres, f32x2* __restrict__ cf8,
                  float* __restrict__ meta, float* __restrict__ gS)
{
    __shared__ u32 h[736];
    __shared__ u32 T[8];
    const int tid = threadIdx.x;
    if (tid < 736) h[tid] = 0u;
    if (tid < 8)   T[tid] = 0u;
    if (tid < NSLOT) gS[tid] = 0.f;
    __syncthreads();
    for (int i = tid; i < N_ROWS; i += 768) atomicAdd(&h[rres[i]], 1u);
    __syncthreads();
    if (tid < 729) { u32 x = h[tid]; if (x > 1) atomicAdd(&T[6], x * (x - 1) / 2u); }
    __syncthreads();
    if (tid < 243) h[tid] = h[tid] + h[tid + 243] + h[tid + 486];
    __syncthreads();
    if (tid < 243) { u32 x = h[tid]; if (x > 1) atomicAdd(&T[5], x * (x - 1) / 2u); }
    __syncthreads();
    if (tid < 81) h[tid] = h[tid] + h[tid + 81] + h[tid + 162];
    __syncthreads();
    if (tid < 81) { u32 x = h[tid]; if (x > 1) atomicAdd(&T[4], x * (x - 1) / 2u); }
    __syncthreads();
    if (tid < 27) h[tid] = h[tid] + h[tid + 27] + h[tid + 54];
    __syncthreads();
    if (tid < 27) { u32 x = h[tid]; if (x > 1) atomicAdd(&T[3], x * (x - 1) / 2u); }
    __syncthreads();
    if (tid < 9) h[tid] = h[tid] + h[tid + 9] + h[tid + 18];
    __syncthreads();
    if (tid < 9) { u32 x = h[tid]; if (x > 1) atomicAdd(&T[2], x * (x - 1) / 2u); }
    __syncthreads();
    if (tid < 3) h[tid] = h[tid] + h[tid + 3] + h[tid + 6];
    __syncthreads();
    if (tid < 3) { u32 x = h[tid]; if (x > 1) atomicAdd(&T[1], x * (x - 1) / 2u); }
    __syncthreads();
    if (tid == 0) {
        u32 cnt[6];
        cnt[0] = (u32)((u64)N_ROWS * (N_ROWS - 1) / 2) - T[1];
        cnt[1] = T[1] - T[2]; cnt[2] = T[2] - T[3]; cnt[3] = T[3] - T[4];
        cnt[4] = T[4] - T[5]; cnt[5] = T[5] - T[6];
        const float w[6]   = {1.f, 0.5f, 1.f / 3.f, 0.25f, 0.2f, 1.f / 6.f};
        const float tvs[6] = {1.f, 1.f / 3.f, 1.f / 9.f, 1.f / 27.f,
                              1.f / 81.f, 1.f / 243.f};
        float lc = 0.f;
#pragma unroll
        for (int v = 0; v < 6; ++v) {
            const bool use = cnt[v] >= 2u;
            cf8[v] = (f32x2){use ? w[v] / (float)cnt[v] : 0.f, tvs[v]};
            lc += use ? 1.f : 0.f;
        }
        cf8[6] = (f32x2){0.f, 0.f};
        cf8[7] = (f32x2){0.f, 0.f};
        meta[0] = (lc > 0.f) ? lc : 1.f;
    }
}

// ---------------------------------------------------------------------------
// Main: R10's PROVEN 64x64 one-wave k-loop (glds superblocks + counted
// vmcnt(8), zero barriers). Epilogue: inline magic-test valuation (register-
// only, proven) + 8-entry LDS (coef, tv) table (lanes hit <=7 distinct 8B
// entries -> broadcast-class ds_read, NOT a scatter) + single-S reduction.
// ---------------------------------------------------------------------------
template<bool DIAG>
__device__ __forceinline__ void epilogue_acc(
    const f32x4 (&acc)[4][4], const float* sqI, const float* sqJ,
    const int* rI, const int* rJ, const f32x2* tbl, int lane, float& S)
{
    const int rbase = (lane >> 4) * 4;   // C/D: row=(lane>>4)*4+q, col=lane&15
    const int cbase = lane & 15;
#pragma unroll
    for (int m = 0; m < 4; ++m) {
        const int il0 = m * 16 + rbase;
#pragma unroll
        for (int n = 0; n < 4; ++n) {
            const int jl  = n * 16 + cbase;
            const float sqj = sqJ[jl];
            const int   rj  = rJ[jl];
#pragma unroll
            for (int q = 0; q < 4; ++q) {
                const int il = il0 + q;
                float d2 = fmaxf(sqI[il] + sqj - 2.0f * acc[m][n][q], 0.f);
                const float dist = __builtin_amdgcn_sqrtf(d2);
                int dm = rI[il] - rj;
                dm += (dm >> 31) & MOD3;               // [0, 729)
                const u32 x = (u32)dm;
                // v3 valuation capped at 6 (PROVEN): 3^t|x <=> x*inv3^t <= thr
                const int v =
                    (x * 2863311531u <= 1431655765u) +   // 3
                    (x *  954437177u <=  477218588u) +   // 9
                    (x * 1749801491u <=  159072862u) +   // 27
                    (x * 2014922929u <=   53024287u) +   // 81
                    (x * 3534952507u <=   17674762u) +   // 243
                    (x * 4041629033u <=    5891587u);    // 729 (x==0 -> 6)
                const f32x2 ct = tbl[v];               // (coef, tv); v=6 -> 0
                float coef = ct[0];
                if (DIAG) coef = (jl > il) ? coef : 0.f;
                const float dd = dist - ct[1];
                S += coef * dd * dd;
            }
        }
    }
}

__global__ __launch_bounds__(64, 2)
void pair_kernel(const u64* __restrict__ zpack, const float* __restrict__ sq,
                 const int* __restrict__ rres, const f32x2* __restrict__ cf8,
                 float* __restrict__ gS)
{
    __shared__ __align__(16) u64 sb[2][8][128];   // 16 KB: 4 A + 4 B superblocks
    __shared__ float sqI[64], sqJ[64];
    __shared__ int   rI[64], rJ[64];
    __shared__ f32x2 tbl[8];

    const int lane = threadIdx.x;

    // bijective XCD swizzle (2080 = 8 * 260)
    const int wg = (blockIdx.x & 7) * (NPAIR64 / 8) + (blockIdx.x >> 3);
    int t = wg, ti = 0, rem = NT64;
    while (t >= rem) { t -= rem; ++ti; --rem; }
    const int tj = ti + t;
    const int I0 = ti * 64, J0 = tj * 64;

    // coef/tv table: 8 lanes load+stage (wave-internal lgkmcnt orders it)
    if (lane < 8) tbl[lane] = cf8[lane];

    // aux staging (4 glds; retired by the first vmcnt(8))
    __builtin_amdgcn_global_load_lds(
        (const __attribute__((address_space(1))) u32*)(sq + I0 + lane),
        (__attribute__((address_space(3))) u32*)sqI, 4, 0, 0);
    __builtin_amdgcn_global_load_lds(
        (const __attribute__((address_space(1))) u32*)(sq + J0 + lane),
        (__attribute__((address_space(3))) u32*)sqJ, 4, 0, 0);
    __builtin_amdgcn_global_load_lds(
        (const __attribute__((address_space(1))) u32*)(rres + I0 + lane),
        (__attribute__((address_space(3))) u32*)rI, 4, 0, 0);
    __builtin_amdgcn_global_load_lds(
        (const __attribute__((address_space(1))) u32*)(rres + J0 + lane),
        (__attribute__((address_space(3))) u32*)rJ, 4, 0, 0);

    const int RA = ti * 4, RB = tj * 4;   // 16-row group bases

#define STAGE(buf, kp)                                                         \
    {                                                                          \
        _Pragma("unroll")                                                      \
        for (int g = 0; g < 4; ++g) {                                          \
            __builtin_amdgcn_global_load_lds(                                  \
                (const __attribute__((address_space(1))) u32*)                 \
                    (zpack + (((size_t)(RA + g) * 8 + (kp)) << 7) + lane * 2), \
                (__attribute__((address_space(3))) u32*)&sb[buf][g][0],        \
                16, 0, 0);                                                     \
            __builtin_amdgcn_global_load_lds(                                  \
                (const __attribute__((address_space(1))) u32*)                 \
                    (zpack + (((size_t)(RB + g) * 8 + (kp)) << 7) + lane * 2), \
                (__attribute__((address_space(3))) u32*)&sb[buf][4 + g][0],    \
                16, 0, 0);                                                     \
        }                                                                      \
    }

    f32x4 acc[4][4];
#pragma unroll
    for (int m = 0; m < 4; ++m)
#pragma unroll
        for (int n = 0; n < 4; ++n) acc[m][n] = (f32x4){0.f, 0.f, 0.f, 0.f};

    STAGE(0, 0);
#pragma unroll
    for (int kp = 0; kp < NKP; ++kp) {
        const int buf = kp & 1;
        if (kp + 1 < NKP) {
            STAGE(buf ^ 1, kp + 1);
            asm volatile("s_waitcnt vmcnt(8)" ::: "memory");
        } else {
            asm volatile("s_waitcnt vmcnt(0)" ::: "memory");
        }
        __builtin_amdgcn_sched_barrier(0);
        long2v A[4], B[4];
#pragma unroll
        for (int g = 0; g < 4; ++g) {
            A[g] = reinterpret_cast<const long2v*>(&sb[buf][g][0])[lane];
            B[g] = reinterpret_cast<const long2v*>(&sb[buf][4 + g][0])[lane];
        }
#pragma unroll
        for (int h = 0; h < 2; ++h)
#pragma unroll
            for (int m = 0; m < 4; ++m)
#pragma unroll
                for (int n = 0; n < 4; ++n)
                    acc[m][n] = __builtin_amdgcn_mfma_f32_16x16x32_fp8_fp8(
                        A[m][h], B[n][h], acc[m][n], 0, 0, 0);
    }
#undef STAGE

    // ---- fused epilogue (1 wave, no barriers) ----
    float S = 0.f;
    if (ti == tj) epilogue_acc<true >(acc, sqI, sqJ, rI, rJ, tbl, lane, S);
    else          epilogue_acc<false>(acc, sqI, sqJ, rI, rJ, tbl, lane, S);

#pragma unroll
    for (int off = 32; off > 0; off >>= 1) S += __shfl_xor(S, off, 64);
    if (lane == 0) atomicAdd(&gS[blockIdx.x & (NSLOT - 1)], S);
}

// ---------------------------------------------------------------------------
__global__ __launch_bounds__(64)
void finalize_kernel(const float* __restrict__ gS,
                     const float* __restrict__ meta, float* __restrict__ out)
{
    const int lane = threadIdx.x;
    float s = gS[lane];
#pragma unroll
    for (int off = 32; off > 0; off >>= 1) s += __shfl_xor(s, off, 64);
    if (lane == 0) out[0] = s / meta[0];
}

// ---------------------------------------------------------------------------
extern "C" void kernel_launch(void* const* d_in, const int* in_sizes, int n_in,
                              void* d_out, int out_size, void* d_ws, size_t ws_size,
                              hipStream_t stream)
{
    const float* z   = (const float*)d_in[0];
    const int*   idx = (const int*)d_in[1];
    char* ws = (char*)d_ws;
    u64*   zpk  = (u64*)(ws + WS_ZPK);
    float* sq   = (float*)(ws + WS_SQ);
    int*   rres = (int*)(ws + WS_R);
    float* gS   = (float*)(ws + WS_GS);
    float* meta = (float*)(ws + WS_META);
    f32x2* cf8  = (f32x2*)(ws + WS_CF8);
    float* out  = (float*)d_out;

    prep_kernel<<<N_ROWS / 4, 256, 0, stream>>>(z, idx, zpk, sq, rres);
    count_kernel<<<1, 768, 0, stream>>>(rres, cf8, meta, gS);
    pair_kernel<<<NPAIR64, 64, 0, stream>>>(zpk, sq, rres, cf8, gS);
    finalize_kernel<<<1, 64, 0, stream>>>(gS, meta, out);
}